// Round 1
// baseline (142.221 us; speedup 1.0000x reference)
//
#include <hip/hip_runtime.h>

typedef _Float16 half8  __attribute__((ext_vector_type(8)));
typedef _Float16 half2v __attribute__((ext_vector_type(2)));
typedef float    f32x4  __attribute__((ext_vector_type(4)));

#define BB    16      // bond feature dim
#define KB    17      // bond features + bias-one feature
#define NSTEP 34      // K=1088 / 32
#define BM    256     // edges per block

__global__ void zero_f32(f32x4* __restrict__ p, int n4) {
  int i = blockIdx.x * blockDim.x + threadIdx.x;
  if (i < n4) p[i] = (f32x4){0.f, 0.f, 0.f, 0.f};
}

// Pack M2[i][k] (i=0..63, k=0..1087) into fragment-major f16 layout:
// for (s,t,lane,e): value = M2[t*16 + (lane&15)][s*32 + (lane>>4)*8 + e]
// M2[i][b*64+j] = kernel[b][i*64+j] for b<16, = bias[i*64+j] for b==16.
__global__ void pack_kt(const float* __restrict__ kern, const float* __restrict__ bias,
                        _Float16* __restrict__ ktg) {
  int g = blockIdx.x * blockDim.x + threadIdx.x;   // one thread per (s,t,lane)
  int s = g >> 8, t = (g >> 6) & 3, l = g & 63;
  int i = t * 16 + (l & 15);
  int k0 = s * 32 + (l >> 4) * 8;
  _Float16 v[8];
#pragma unroll
  for (int e = 0; e < 8; ++e) {
    int k = k0 + e, b = k >> 6, j = k & 63;
    float x = (b < BB) ? kern[b * 4096 + i * 64 + j] : bias[i * 64 + j];
    v[e] = (_Float16)x;
  }
  *(half8*)(ktg + (size_t)g * 8) = *(const half8*)v;
}

// Fused: transformed = X @ M2^T with X[e, b*64+j] = bond[e,b]*nb[e,j],
// then atomicAdd rows into out[src(e)].
__global__ __launch_bounds__(256, 3)
void edge_gemm(const float* __restrict__ atom, const float* __restrict__ bond,
               const int* __restrict__ pair, const _Float16* __restrict__ ktg,
               float* __restrict__ out, int E) {
  __shared__ _Float16 nb[BM * 64];   // gathered neighbor rows, f16, XOR-swizzled (32 KB)
  __shared__ float bnd[BM * KB];     // bond + implicit 1.0 (17.4 KB)
  __shared__ int srcs[BM];

  const int tid = threadIdx.x;
  const int e0  = blockIdx.x * BM;

  { // ---- staging: gather 256 edges ----
    int e = e0 + tid;
    bool valid = e < E;
    int nbr = 0;
    if (valid) { nbr = pair[2 * e + 1]; srcs[tid] = pair[2 * e]; }
    else       { srcs[tid] = 0; }
    const f32x4* brow = (const f32x4*)(bond + (size_t)e * BB);
#pragma unroll
    for (int q = 0; q < 4; ++q) {
      f32x4 bv = {0.f, 0.f, 0.f, 0.f};
      if (valid) bv = brow[q];
#pragma unroll
      for (int z = 0; z < 4; ++z) bnd[tid * KB + q * 4 + z] = bv[z];
    }
    bnd[tid * KB + 16] = valid ? 1.0f : 0.0f;   // bias feature (0 for padded edges)

    const f32x4* arow = (const f32x4*)(atom + (size_t)nbr * 64);
#pragma unroll
    for (int c = 0; c < 8; ++c) {               // 8 chunks of 8 f16 per row
      f32x4 x0 = arow[2 * c], x1 = arow[2 * c + 1];
      _Float16 h[8];
      h[0] = (_Float16)x0[0]; h[1] = (_Float16)x0[1]; h[2] = (_Float16)x0[2]; h[3] = (_Float16)x0[3];
      h[4] = (_Float16)x1[0]; h[5] = (_Float16)x1[1]; h[6] = (_Float16)x1[2]; h[7] = (_Float16)x1[3];
      int dst = tid * 128 + ((c ^ (tid & 7)) << 4);   // byte offset, XOR swizzle
      *(half8*)((char*)nb + dst) = *(const half8*)h;
    }
  }
  __syncthreads();

  const int lane = tid & 63, wave = tid >> 6;
  const int wm = wave >> 1, wn = wave & 1;     // 2(M) x 2(N) waves
  const int l15 = lane & 15, lg = lane >> 4;

  f32x4 acc[8][2];
#pragma unroll
  for (int mt = 0; mt < 8; ++mt) {
    acc[mt][0] = (f32x4){0.f, 0.f, 0.f, 0.f};
    acc[mt][1] = (f32x4){0.f, 0.f, 0.f, 0.f};
  }

  // K split across grid.y: y=0 -> b 0..8 (s 0..17), y=1 -> b 9..16 (s 18..33)
  const int sBeg = blockIdx.y ? 18 : 0;
  const int sEnd = blockIdx.y ? NSTEP : 18;

  int rowb[8], rows7[8];
#pragma unroll
  for (int mt = 0; mt < 8; ++mt) {
    int row = wm * 128 + mt * 16 + l15;
    rowb[mt]  = row * 128;          // byte base of LDS row
    rows7[mt] = (row & 7) << 4;     // swizzle bits
  }

  half2v sc[8];
  int bprev = -1;
  for (int s = sBeg; s < sEnd; ++s) {
    // B fragments straight from L2 (fragment-major, coalesced 16B/lane)
    const half8 bf0 = *(const half8*)(ktg + ((size_t)(s * 4 + wn * 2    ) * 64 + lane) * 8);
    const half8 bf1 = *(const half8*)(ktg + ((size_t)(s * 4 + wn * 2 + 1) * 64 + lane) * 8);
    const int b = s >> 1;
    if (b != bprev) {               // refresh bond scales every 2 k-steps
      bprev = b;
#pragma unroll
      for (int mt = 0; mt < 8; ++mt) {
        _Float16 sh = (_Float16)bnd[(wm * 128 + mt * 16 + l15) * KB + b];
        sc[mt] = (half2v){sh, sh};
      }
    }
    const int coff = ((s & 1) * 4 + lg) << 4;   // byte offset of this k-step's chunk
#pragma unroll
    for (int mt = 0; mt < 8; ++mt) {
      half8 a = *(const half8*)((const char*)nb + (rowb[mt] + (coff ^ rows7[mt])));
      half2v* a2 = (half2v*)&a;
#pragma unroll
      for (int q = 0; q < 4; ++q) a2[q] = a2[q] * sc[mt];   // X = bond * nb (v_pk_mul_f16)
      acc[mt][0] = __builtin_amdgcn_mfma_f32_16x16x32_f16(a, bf0, acc[mt][0], 0, 0, 0);
      acc[mt][1] = __builtin_amdgcn_mfma_f32_16x16x32_f16(a, bf1, acc[mt][1], 0, 0, 0);
    }
  }

  // ---- epilogue: segment-sum via device-scope atomics ----
#pragma unroll
  for (int mt = 0; mt < 8; ++mt) {
    const int elb = wm * 128 + mt * 16 + lg * 4;
#pragma unroll
    for (int r = 0; r < 4; ++r) {
      const int el = elb + r;
      if (e0 + el < E) {
        const int dst = srcs[el] * 64 + wn * 32 + l15;
        atomicAdd(out + dst,      acc[mt][0][r]);
        atomicAdd(out + dst + 16, acc[mt][1][r]);
      }
    }
  }
}

extern "C" void kernel_launch(void* const* d_in, const int* in_sizes, int n_in,
                              void* d_out, int out_size, void* d_ws, size_t ws_size,
                              hipStream_t stream) {
  const float* atom = (const float*)d_in[0];
  const float* bond = (const float*)d_in[1];
  const int*   pair = (const int*)d_in[2];
  const float* kern = (const float*)d_in[3];
  const float* bias = (const float*)d_in[4];
  float* out = (float*)d_out;
  _Float16* ktg = (_Float16*)d_ws;   // 34*4*64*8 f16 = 139,264 B

  const int E  = in_sizes[1] / BB;
  const int n4 = out_size / 4;

  zero_f32<<<(n4 + 255) / 256, 256, 0, stream>>>((f32x4*)out, n4);
  pack_kt<<<NSTEP, 256, 0, stream>>>(kern, bias, ktg);
  dim3 grid((E + BM - 1) / BM, 2);
  edge_gemm<<<grid, 256, 0, stream>>>(atom, bond, pair, ktg, out, E);
}

// Round 2
// 116.034 us; speedup vs baseline: 1.2257x; 1.2257x over previous
//
#include <hip/hip_runtime.h>

typedef _Float16 half8  __attribute__((ext_vector_type(8)));
typedef _Float16 half2v __attribute__((ext_vector_type(2)));
typedef float    f32x4  __attribute__((ext_vector_type(4)));

#define BB    16      // bond feature dim
#define KB    17      // bond features + bias-one feature
#define NSTEP 34      // K = 17*64 / 32
#define BM    128     // edges per block

// Pack M2[i][k] (i=0..63, k=0..1087) into fragment-major f16 layout:
// for (s,t,lane,e): value = M2[t*16 + (lane&15)][s*32 + (lane>>4)*8 + e]
// M2[i][b*64+j] = kernel[b][i*64+j] for b<16, = bias[i*64+j] for b==16.
__global__ void pack_kt(const float* __restrict__ kern, const float* __restrict__ bias,
                        _Float16* __restrict__ ktg) {
  int g = blockIdx.x * blockDim.x + threadIdx.x;   // one thread per (s,t,lane)
  int s = g >> 8, t = (g >> 6) & 3, l = g & 63;
  int i = t * 16 + (l & 15);
  int k0 = s * 32 + (l >> 4) * 8;
  _Float16 v[8];
#pragma unroll
  for (int e = 0; e < 8; ++e) {
    int k = k0 + e, b = k >> 6, j = k & 63;
    float x = (b < BB) ? kern[b * 4096 + i * 64 + j] : bias[i * 64 + j];
    v[e] = (_Float16)x;
  }
  *(half8*)(ktg + (size_t)g * 8) = *(const half8*)v;
}

// Fused: transformed = X @ M2^T with X[e, b*64+j] = bond[e,b]*nb[e,j],
// then atomicAdd rows into out[src(e)]. Full K per block (no split).
__global__ __launch_bounds__(256, 4)
void edge_gemm(const float* __restrict__ atom, const float* __restrict__ bond,
               const int* __restrict__ pair, const _Float16* __restrict__ ktg,
               float* __restrict__ out, int E) {
  __shared__ _Float16 nb[BM * 64];   // gathered neighbor rows, f16, XOR-swizzled (16 KB)
  __shared__ float bnd[BM * KB];     // bond + implicit 1.0 (8.7 KB)
  __shared__ int srcs[BM];

  const int tid = threadIdx.x;
  const int e0  = blockIdx.x * BM;
  const int row = tid >> 1, half = tid & 1;

  { // ---- staging: 2 threads per edge ----
    const int e = e0 + row;
    const bool valid = e < E;
    int nbr = 0;
    if (half == 0) srcs[row] = valid ? pair[2 * e] : 0;
    if (valid) nbr = pair[2 * e + 1];

    const f32x4* brow = (const f32x4*)(bond + (size_t)e * BB);
#pragma unroll
    for (int q = 0; q < 2; ++q) {
      f32x4 bv = {0.f, 0.f, 0.f, 0.f};
      if (valid) bv = brow[half * 2 + q];
#pragma unroll
      for (int z = 0; z < 4; ++z) bnd[row * KB + (half * 2 + q) * 4 + z] = bv[z];
    }
    if (half) bnd[row * KB + 16] = valid ? 1.0f : 0.0f;  // bias feature

    const f32x4* arow = (const f32x4*)(atom + (size_t)nbr * 64);
#pragma unroll
    for (int cc = 0; cc < 4; ++cc) {
      const int c8 = half * 4 + cc;                // 16B chunk index within row
      f32x4 x0 = {0.f,0.f,0.f,0.f}, x1 = {0.f,0.f,0.f,0.f};
      if (valid) { x0 = arow[2 * c8]; x1 = arow[2 * c8 + 1]; }
      _Float16 h[8];
      h[0] = (_Float16)x0[0]; h[1] = (_Float16)x0[1]; h[2] = (_Float16)x0[2]; h[3] = (_Float16)x0[3];
      h[4] = (_Float16)x1[0]; h[5] = (_Float16)x1[1]; h[6] = (_Float16)x1[2]; h[7] = (_Float16)x1[3];
      const int dst = row * 128 + ((c8 ^ (row & 7)) << 4);   // byte offset, XOR swizzle
      *(half8*)((char*)nb + dst) = *(const half8*)h;
    }
  }
  __syncthreads();

  const int lane = tid & 63, wave = tid >> 6;
  const int l15 = lane & 15, lg = lane >> 4;
  const int r0 = wave * 32 + l15, r1 = r0 + 16;    // the wave's two 16-row tiles
  const int row0b = r0 * 128, row0s = (r0 & 7) << 4;
  const int row1b = r1 * 128, row1s = (r1 & 7) << 4;

  f32x4 acc[2][4];
#pragma unroll
  for (int mt = 0; mt < 2; ++mt)
#pragma unroll
    for (int nt = 0; nt < 4; ++nt)
      acc[mt][nt] = (f32x4){0.f, 0.f, 0.f, 0.f};

  // B fragments straight from L2 (fragment-major, coalesced 16B/lane),
  // software-pipelined one step ahead.
  const _Float16* bp = ktg + (size_t)lane * 8;
  half8 b0 = *(const half8*)(bp + 0 * 512);
  half8 b1 = *(const half8*)(bp + 1 * 512);
  half8 b2 = *(const half8*)(bp + 2 * 512);
  half8 b3 = *(const half8*)(bp + 3 * 512);
  float s0 = bnd[r0 * KB], s1 = bnd[r1 * KB];

#pragma unroll 2
  for (int s = 0; s < NSTEP; ++s) {
    // ---- prefetch next step's B fragments + scales ----
    const int sn = (s + 1 < NSTEP) ? s + 1 : s;
    half8 n0 = *(const half8*)(bp + (sn * 4 + 0) * 512);
    half8 n1 = *(const half8*)(bp + (sn * 4 + 1) * 512);
    half8 n2 = *(const half8*)(bp + (sn * 4 + 2) * 512);
    half8 n3 = *(const half8*)(bp + (sn * 4 + 3) * 512);
    float t0 = s0, t1 = s1;
    if (((s + 1) & 1) == 0) {                      // b changes on even steps
      const int bn = ((s + 1) >> 1) > 16 ? 16 : ((s + 1) >> 1);
      t0 = bnd[r0 * KB + bn];
      t1 = bnd[r1 * KB + bn];
    }

    // ---- compute current step ----
    const int coff = ((s & 1) * 4 + lg) << 4;      // byte offset of this k-chunk
    const half2v sc0 = {(_Float16)s0, (_Float16)s0};
    const half2v sc1 = {(_Float16)s1, (_Float16)s1};

    half8 a0 = *(const half8*)((const char*)nb + (row0b + (coff ^ row0s)));
    {
      half2v* a2 = (half2v*)&a0;
#pragma unroll
      for (int q = 0; q < 4; ++q) a2[q] = a2[q] * sc0;   // X = bond * nb
    }
    acc[0][0] = __builtin_amdgcn_mfma_f32_16x16x32_f16(a0, b0, acc[0][0], 0, 0, 0);
    acc[0][1] = __builtin_amdgcn_mfma_f32_16x16x32_f16(a0, b1, acc[0][1], 0, 0, 0);
    acc[0][2] = __builtin_amdgcn_mfma_f32_16x16x32_f16(a0, b2, acc[0][2], 0, 0, 0);
    acc[0][3] = __builtin_amdgcn_mfma_f32_16x16x32_f16(a0, b3, acc[0][3], 0, 0, 0);

    half8 a1 = *(const half8*)((const char*)nb + (row1b + (coff ^ row1s)));
    {
      half2v* a2 = (half2v*)&a1;
#pragma unroll
      for (int q = 0; q < 4; ++q) a2[q] = a2[q] * sc1;
    }
    acc[1][0] = __builtin_amdgcn_mfma_f32_16x16x32_f16(a1, b0, acc[1][0], 0, 0, 0);
    acc[1][1] = __builtin_amdgcn_mfma_f32_16x16x32_f16(a1, b1, acc[1][1], 0, 0, 0);
    acc[1][2] = __builtin_amdgcn_mfma_f32_16x16x32_f16(a1, b2, acc[1][2], 0, 0, 0);
    acc[1][3] = __builtin_amdgcn_mfma_f32_16x16x32_f16(a1, b3, acc[1][3], 0, 0, 0);

    b0 = n0; b1 = n1; b2 = n2; b3 = n3; s0 = t0; s1 = t1;
  }

  // ---- epilogue: segment-sum via device-scope atomics (fire-and-forget) ----
#pragma unroll
  for (int mt = 0; mt < 2; ++mt) {
    const int elb = wave * 32 + mt * 16 + lg * 4;
#pragma unroll
    for (int r = 0; r < 4; ++r) {
      const int el = elb + r;
      if (e0 + el < E) {
        const int dstb = srcs[el] * 64 + l15;
        atomicAdd(out + dstb,      acc[mt][0][r]);
        atomicAdd(out + dstb + 16, acc[mt][1][r]);
        atomicAdd(out + dstb + 32, acc[mt][2][r]);
        atomicAdd(out + dstb + 48, acc[mt][3][r]);
      }
    }
  }
}

extern "C" void kernel_launch(void* const* d_in, const int* in_sizes, int n_in,
                              void* d_out, int out_size, void* d_ws, size_t ws_size,
                              hipStream_t stream) {
  const float* atom = (const float*)d_in[0];
  const float* bond = (const float*)d_in[1];
  const int*   pair = (const int*)d_in[2];
  const float* kern = (const float*)d_in[3];
  const float* bias = (const float*)d_in[4];
  float* out = (float*)d_out;
  _Float16* ktg = (_Float16*)d_ws;   // 34*4*64*8 f16 = 139,264 B

  const int E = in_sizes[1] / BB;

  hipMemsetAsync(out, 0, (size_t)out_size * sizeof(float), stream);
  pack_kt<<<NSTEP, 256, 0, stream>>>(kern, bias, ktg);
  edge_gemm<<<(E + BM - 1) / BM, 256, 0, stream>>>(atom, bond, pair, ktg, out, E);
}